// Round 1
// baseline (216.893 us; speedup 1.0000x reference)
//
#include <hip/hip_runtime.h>

// SpanRepresentation: out[b,s,:] = concat(x[b,start(s),:], x[b,end(s)-1,:], wemb[bucket(s),:])
// B=8, L=512, D=768, WDIM=20, widths 1..8, S=4068, row=1556 floats (=389 float4).

#define B_DIM 8
#define L_DIM 512
#define D_DIM 768
#define W_DIM 20
#define S_TOT 4068
#define ROWF (2 * D_DIM + W_DIM)   // 1556 floats
#define ROW4 (ROWF / 4)            // 389 float4
#define D4 (D_DIM / 4)             // 192 float4

__global__ __launch_bounds__(128) void span_rep_kernel(
    const float* __restrict__ x,
    const float* __restrict__ wemb,
    float* __restrict__ out)
{
    const int s = blockIdx.x;   // span index, wave-uniform
    const int b = blockIdx.y;

    // Decode span index -> (width w, start). Widths w=1..8, counts L-w+1,
    // enumerated in order w=1,2,... matching the reference loop.
    int rem = s;
    int w = 1;
    #pragma unroll 8
    while (rem >= (L_DIM - w + 1)) { rem -= (L_DIM - w + 1); ++w; }
    const int start = rem;
    const int endm1 = start + w - 1;

    // bucket(w) for w=1..8 -> {1,2,3,4,5,5,6,7}; nibble-packed (idx0 unused).
    const int bucket = (int)((0x765543210ull >> (4 * w)) & 0xF);

    const float4* __restrict__ xs =
        reinterpret_cast<const float4*>(x + ((size_t)b * L_DIM + start) * D_DIM);
    const float4* __restrict__ xe =
        reinterpret_cast<const float4*>(x + ((size_t)b * L_DIM + endm1) * D_DIM);
    const float4* __restrict__ we =
        reinterpret_cast<const float4*>(wemb + (size_t)bucket * W_DIM);
    float4* __restrict__ o =
        reinterpret_cast<float4*>(out + ((size_t)b * S_TOT + s) * (size_t)ROWF);

    for (int j = threadIdx.x; j < ROW4; j += 128) {
        float4 v;
        if (j < D4)            v = xs[j];
        else if (j < 2 * D4)   v = xe[j - D4];
        else                   v = we[j - 2 * D4];
        o[j] = v;
    }
}

extern "C" void kernel_launch(void* const* d_in, const int* in_sizes, int n_in,
                              void* d_out, int out_size, void* d_ws, size_t ws_size,
                              hipStream_t stream) {
    const float* x    = (const float*)d_in[0];  // (8, 512, 768) f32
    const float* wemb = (const float*)d_in[1];  // (14, 20) f32
    float* out = (float*)d_out;                 // (8, 4068, 1556) f32

    dim3 grid(S_TOT, B_DIM);
    span_rep_kernel<<<grid, 128, 0, stream>>>(x, wemb, out);
}